// Round 12
// baseline (184.317 us; speedup 1.0000x reference)
//
#include <hip/hip_runtime.h>

// Problem constants: B=2, N=2048, C=1024, H=16, hd=64
// x:(2,2048,1024) f32; Wqkv:(1024,3072); Wproj:(1024,1024); bproj:(1024); q_scale,k_scale:(64)
// out:(2,2048,1024) f32

typedef _Float16 half_t;
typedef __attribute__((ext_vector_type(2))) __fp16 fp16x2;
typedef __attribute__((ext_vector_type(4))) _Float16 half4v;
typedef __attribute__((ext_vector_type(8))) _Float16 half8;
typedef __attribute__((ext_vector_type(4))) float f32x4;
typedef __attribute__((ext_vector_type(4))) unsigned uint4v;

#define DI __device__ __forceinline__

DI void gl_lds16(const void* g, void* l) {
    __builtin_amdgcn_global_load_lds((const __attribute__((address_space(1))) void*)g,
                                     (__attribute__((address_space(3))) void*)l, 16, 0, 0);
}

DI float exp2_fast(float x) {
    float r;
    asm("v_exp_f32 %0, %1" : "=v"(r) : "v"(x));
    return r;
}

// v_permlane32_swap_b32: a.rows[2,3] <-> b.rows[0,1] (rows = 16-lane groups)
DI void pl32_swap(unsigned& a, unsigned& b) {
    asm("v_permlane32_swap_b32 %0, %1" : "+v"(a), "+v"(b));
}
// v_permlane16_swap_b32: a.rows[1,3] <-> b.rows[0,2]
DI void pl16_swap(unsigned& a, unsigned& b) {
    asm("v_permlane16_swap_b32 %0, %1" : "+v"(a), "+v"(b));
}

DI unsigned pk_u32(float lo, float hi) {
    fp16x2 t = __builtin_amdgcn_cvt_pkrtz(lo, hi);
    return *(unsigned*)&t;
}

// ---------------- merged prep kernel ----------------
// blocks [0,4096): x f32->fp16 ; [4096,7168): Wqkv transpose->fp16 ; [7168,8192): Wproj
__global__ void prep_all(const float* __restrict__ x, const float* __restrict__ Wqkv,
                         const float* __restrict__ Wproj, half_t* __restrict__ xh,
                         half_t* __restrict__ wqt, half_t* __restrict__ wpt) {
    __shared__ float t[32][33];
    int bid = blockIdx.x;
    if (bid < 4096) {
        int i = (bid * 256 + threadIdx.x) * 4;
        float4 v = *(const float4*)(x + i);
        half4v o;
        o[0] = (half_t)v.x; o[1] = (half_t)v.y; o[2] = (half_t)v.z; o[3] = (half_t)v.w;
        *(half4v*)(xh + i) = o;
    } else if (bid < 4096 + 3072) {
        int i = bid - 4096;
        int c0 = (i % 96) * 32, r0 = (i / 96) * 32;
        int tx = threadIdx.x & 31, ty = threadIdx.x >> 5;
#pragma unroll
        for (int k = 0; k < 4; k++)
            t[ty + 8 * k][tx] = Wqkv[(size_t)(r0 + ty + 8 * k) * 3072 + c0 + tx];
        __syncthreads();
#pragma unroll
        for (int k = 0; k < 4; k++)
            wqt[(size_t)(c0 + ty + 8 * k) * 1024 + r0 + tx] = (half_t)t[tx][ty + 8 * k];
    } else {
        int i = bid - 4096 - 3072;
        int c0 = (i % 32) * 32, r0 = (i / 32) * 32;
        int tx = threadIdx.x & 31, ty = threadIdx.x >> 5;
#pragma unroll
        for (int k = 0; k < 4; k++)
            t[ty + 8 * k][tx] = Wproj[(size_t)(r0 + ty + 8 * k) * 1024 + c0 + tx];
        __syncthreads();
#pragma unroll
        for (int k = 0; k < 4; k++)
            wpt[(size_t)(c0 + ty + 8 * k) * 1024 + r0 + tx] = (half_t)t[tx][ty + 8 * k];
    }
}

// ---------------- QKV GEMM: fp16, BK=64, dbuf LDS, fused RMSNorm epilogue ----------------
__global__ __launch_bounds__(256) void gemm_qkv(
    const half_t* __restrict__ A, const half_t* __restrict__ Bt,
    const float* __restrict__ qs, const float* __restrict__ ks,
    half_t* __restrict__ qh, half_t* __restrict__ kh, half_t* __restrict__ vth) {
    const int K = 1024;
    __shared__ __align__(16) half_t Al[2][128 * 64];
    __shared__ __align__(16) half_t Bl[2][128 * 64];
    int tid = threadIdx.x;
    int w = tid >> 6, l = tid & 63;
    int wr = w >> 1, wc = w & 1;
    int g = l >> 4, r = l & 15;
    int m0 = blockIdx.x * 128, n0 = blockIdx.y * 128;
    f32x4 acc[4][4] = {};

#define STAGE_QKV(kt, buf)                                                        \
    {                                                                             \
        _Pragma("unroll")                                                         \
        for (int p = 0; p < 4; p++) {                                             \
            int ci = p * 256 + tid;                                               \
            int row = ci >> 3, c = ci & 7, lc = c ^ (row & 7);                    \
            gl_lds16(A + (size_t)(m0 + row) * K + (kt) * 64 + lc * 8,             \
                     &Al[buf][0] + ci * 8);                                       \
            gl_lds16(Bt + (size_t)(n0 + row) * K + (kt) * 64 + lc * 8,            \
                     &Bl[buf][0] + ci * 8);                                       \
        }                                                                         \
    }

    STAGE_QKV(0, 0);
    __syncthreads();
    int cur = 0;
    for (int kt = 0; kt < 16; kt++) {
        if (kt < 15) STAGE_QKV(kt + 1, cur ^ 1);
#pragma unroll
        for (int ks2 = 0; ks2 < 2; ks2++) {
            half8 af[4], bf[4];
#pragma unroll
            for (int i = 0; i < 4; i++) {
                int row = wr * 64 + i * 16 + r;
                af[i] = *(const half8*)(&Al[cur][0] + row * 64 + (((4 * ks2 + g) ^ (row & 7)) << 3));
                int rowb = wc * 64 + i * 16 + r;
                bf[i] = *(const half8*)(&Bl[cur][0] + rowb * 64 + (((4 * ks2 + g) ^ (rowb & 7)) << 3));
            }
#pragma unroll
            for (int i = 0; i < 4; i++)
#pragma unroll
                for (int j = 0; j < 4; j++)
                    acc[i][j] = __builtin_amdgcn_mfma_f32_16x16x32_f16(af[i], bf[j], acc[i][j], 0, 0, 0);
        }
        __syncthreads();
        cur ^= 1;
    }

    int tsec = n0 >> 10;  // 0=q, 1=k, 2=v (uniform per block)
    if (tsec == 2) {
#pragma unroll
        for (int i = 0; i < 4; i++)
#pragma unroll
            for (int j = 0; j < 4; j++) {
                int gcol = n0 + wc * 64 + j * 16 + r;
                int h = (gcol >> 6) & 15;
                int f = gcol & 63;
                int growb = m0 + wr * 64 + i * 16 + g * 4;
                int b = growb >> 11;
                int n = growb & 2047;
                half4v pv;
#pragma unroll
                for (int rr = 0; rr < 4; rr++) pv[rr] = (half_t)acc[i][j][rr];
                *(half4v*)(vth + ((size_t)(b * 16 + h) * 64 + f) * 2048 + n) = pv;
            }
    } else {
        const float* sc = (tsec == 0) ? qs : ks;
        half_t* dst = (tsec == 0) ? qh : kh;
        float extra = (tsec == 0) ? (0.125f * 1.44269504f) : 1.0f;  // fold hd^-0.5*log2e into q
        float scv[4];
#pragma unroll
        for (int j = 0; j < 4; j++) scv[j] = sc[j * 16 + r];
#pragma unroll
        for (int i = 0; i < 4; i++)
#pragma unroll
            for (int rr = 0; rr < 4; rr++) {
                float ss = 0.f;
#pragma unroll
                for (int j = 0; j < 4; j++) ss += acc[i][j][rr] * acc[i][j][rr];
#pragma unroll
                for (int d = 1; d < 16; d <<= 1) ss += __shfl_xor(ss, d, 64);
                float inv = extra / (sqrtf(ss) * 0.125f + 1e-8f);  // rms = ||row||/8
                int grow = m0 + wr * 64 + i * 16 + g * 4 + rr;
                int b = grow >> 11;
                int n = grow & 2047;
#pragma unroll
                for (int j = 0; j < 4; j++) {
                    int gcol = n0 + wc * 64 + j * 16 + r;
                    int h = (gcol >> 6) & 15;
                    int f = gcol & 63;
                    dst[((size_t)(b * 16 + h) * 2048 + n) * 64 + f] =
                        (half_t)(acc[i][j][rr] * inv * scv[j]);
                }
            }
    }
}

// ---------------- flash attention main pass: kv-split-2 -----------------------------
// grid (16 q-tiles, 32 bh, 2 kv-halves) = 1024 blocks of 8 waves -> 4 blocks/CU
// (wave-slot max; was grid-limited to 2/CU before — THE occupancy fix).
// Each block: 128 q x 1024 kv (16 tiles), R10 structure (permlane PV, no P-LDS,
// 32KB dbuf LDS). Epilogue: self-normalized partial O_i = o_i/ls_i in fp16 +
// (m_i, ls_i) f32 -> workspace; combine kernel merges halves.
// Defer-max THR=11, predicate-only common path (PROVEN; no-max failed 4.7e-2).
__global__ __launch_bounds__(512, 8) void attn(
    const half_t* __restrict__ qh, const half_t* __restrict__ kh,
    const half_t* __restrict__ vth, half_t* __restrict__ po16,
    float2* __restrict__ pml) {
    int bh = blockIdx.y, hf = blockIdx.z;
    int q0 = blockIdx.x * 128;
    const half_t* Qp = qh + (size_t)bh * 2048 * 64;
    const half_t* Kp = kh + (size_t)bh * 2048 * 64 + (size_t)hf * 1024 * 64;
    const half_t* Vp = vth + (size_t)bh * 64 * 2048 + hf * 1024;  // (feat, n)
    __shared__ __align__(16) half_t Kl[2][64 * 64];
    __shared__ __align__(16) half_t Vl[2][64 * 64];   // [feat][kv]
    int tid = threadIdx.x, w = tid >> 6, l = tid & 63, g = l >> 4, r = l & 15;

    // staging: 512 chunks of 16B per 64x64 fp16 buffer, 1 chunk/thread
    int srow = tid >> 3, sc = tid & 7, slc = sc ^ (srow & 7);
    const half_t* kst = Kp + (size_t)srow * 64 + slc * 8;
    const half_t* vst = Vp + (size_t)srow * 2048 + slc * 8;

    // hoisted LDS element-offsets (loop-invariant)
    int koff[8], voff[8];
#pragma unroll
    for (int ks = 0; ks < 2; ks++)
#pragma unroll
        for (int tt = 0; tt < 4; tt++) {
            int row = tt * 16 + r;
            koff[ks * 4 + tt] = row * 64 + (((4 * ks + g) ^ (row & 7)) << 3);
        }
#pragma unroll
    for (int ks2 = 0; ks2 < 2; ks2++)
#pragma unroll
        for (int cf = 0; cf < 4; cf++) {
            int row = cf * 16 + r;
            voff[ks2 * 4 + cf] = row * 64 + (((4 * ks2 + g) ^ (row & 7)) << 3);
        }

    // Q fragment: Q[q=r][hd = 32ks + 8g + e]  (B-operand of swapped QK^T)
    half8 qf[2];
#pragma unroll
    for (int ks = 0; ks < 2; ks++)
        qf[ks] = *(const half8*)(Qp + (size_t)(q0 + w * 16 + r) * 64 + ks * 32 + g * 8);

    f32x4 o[4] = {};          // O^T[d = 16cf + 4g + reg][q = r]
    float m = -1e30f, lsum = 0.f;  // per-lane partial lsum, reduced in epilogue

    // prologue: stage tile 0
    gl_lds16(kst, &Kl[0][0] + tid * 8);
    gl_lds16(vst, &Vl[0][0] + tid * 8);
    __syncthreads();

#define ATTN_TILE(BUF, T)                                                          \
    {                                                                              \
        if ((T) < 15) {                                                            \
            gl_lds16(kst + ((T) + 1) * 4096, &Kl[(BUF) ^ 1][0] + tid * 8);         \
            gl_lds16(vst + ((T) + 1) * 64, &Vl[(BUF) ^ 1][0] + tid * 8);           \
        }                                                                          \
        const half_t* Kc = &Kl[BUF][0];                                            \
        const half_t* Vc = &Vl[BUF][0];                                            \
        f32x4 s[4] = {};                                                           \
        _Pragma("unroll")                                                          \
        for (int ks = 0; ks < 2; ks++)                                             \
            _Pragma("unroll")                                                      \
            for (int tt = 0; tt < 4; tt++) {                                       \
                half8 kf = *(const half8*)(Kc + koff[ks * 4 + tt]);                \
                s[tt] = __builtin_amdgcn_mfma_f32_16x16x32_f16(kf, qf[ks], s[tt], 0, 0, 0); \
            }                                                                      \
        float thr = m + 11.0f;                                                     \
        bool ok = true;                                                            \
        _Pragma("unroll")                                                          \
        for (int tt = 0; tt < 4; tt++)                                             \
            _Pragma("unroll")                                                      \
            for (int e = 0; e < 4; e++) ok = ok && (s[tt][e] <= thr);              \
        if (!__all(ok)) {                                                          \
            float mx = -1e30f;                                                     \
            _Pragma("unroll")                                                      \
            for (int tt = 0; tt < 4; tt++)                                         \
                mx = fmaxf(mx, fmaxf(fmaxf(s[tt][0], s[tt][1]), fmaxf(s[tt][2], s[tt][3]))); \
            mx = fmaxf(mx, __shfl_xor(mx, 16, 64));                                \
            mx = fmaxf(mx, __shfl_xor(mx, 32, 64));                                \
            float mn = fmaxf(m, mx);                                               \
            float fac = exp2_fast(m - mn);                                         \
            lsum *= fac;                                                           \
            _Pragma("unroll")                                                      \
            for (int cf = 0; cf < 4; cf++) {                                       \
                o[cf][0] *= fac; o[cf][1] *= fac; o[cf][2] *= fac; o[cf][3] *= fac; \
            }                                                                      \
            m = mn;                                                                \
        }                                                                          \
        _Pragma("unroll")                                                          \
        for (int tt = 0; tt < 4; tt++)                                             \
            _Pragma("unroll")                                                      \
            for (int e = 0; e < 4; e++) {                                          \
                float p = exp2_fast(s[tt][e] - m);                                 \
                s[tt][e] = p;                                                      \
                lsum += p;                                                         \
            }                                                                      \
        unsigned W[4][2];                                                          \
        _Pragma("unroll")                                                          \
        for (int tt = 0; tt < 4; tt++) {                                           \
            W[tt][0] = pk_u32(s[tt][0], s[tt][1]);                                 \
            W[tt][1] = pk_u32(s[tt][2], s[tt][3]);                                 \
        }                                                                          \
        _Pragma("unroll")                                                          \
        for (int ks2 = 0; ks2 < 2; ks2++) {                                        \
            unsigned b0 = W[2 * ks2][0], b2 = W[2 * ks2 + 1][0];                   \
            unsigned b1 = W[2 * ks2][1], b3 = W[2 * ks2 + 1][1];                   \
            pl32_swap(b0, b2); pl16_swap(b0, b2);                                  \
            pl32_swap(b1, b3); pl16_swap(b1, b3);                                  \
            uint4v pw; pw[0] = b0; pw[1] = b1; pw[2] = b2; pw[3] = b3;             \
            half8 pf = *(half8*)&pw;                                               \
            _Pragma("unroll")                                                      \
            for (int cf = 0; cf < 4; cf++) {                                       \
                half8 vf = *(const half8*)(Vc + voff[ks2 * 4 + cf]);               \
                o[cf] = __builtin_amdgcn_mfma_f32_16x16x32_f16(vf, pf, o[cf], 0, 0, 0); \
            }                                                                      \
        }                                                                          \
        __syncthreads();                                                           \
    }

    for (int t = 0; t < 16; t += 2) {
        ATTN_TILE(0, t);
        ATTN_TILE(1, t + 1);
    }

    // cross-lane (g-group) sum: lanes r, r+16, r+32, r+48 hold disjoint kv-slots
    lsum += __shfl_xor(lsum, 16, 64);
    lsum += __shfl_xor(lsum, 32, 64);

    int n = q0 + w * 16 + r;
    size_t pq = (size_t)(hf * 32 + bh) * 2048 + n;
    float inv = 1.0f / lsum;
#pragma unroll
    for (int cf = 0; cf < 4; cf++) {
        half4v ov;
#pragma unroll
        for (int reg = 0; reg < 4; reg++) ov[reg] = (half_t)(o[cf][reg] * inv);
        *(half4v*)(po16 + pq * 64 + cf * 16 + g * 4) = ov;
    }
    if (l < 16) pml[pq] = make_float2(m, lsum);
}

// ---------------- combine: merge the two kv-half partials ----------------
// thread i -> (bh, q, d4): 4 consecutive d. out = w0*O0 + w1*O1,
// w_i = ls_i * exp2(m_i - M) / sum_j ls_j * exp2(m_j - M).
__global__ void attn_combine(const half_t* __restrict__ po16,
                             const float2* __restrict__ pml,
                             half_t* __restrict__ aoh) {
    int idx = blockIdx.x * 256 + threadIdx.x;
    int d4 = idx & 15;
    int q = (idx >> 4) & 2047;
    int bh = idx >> 15;
    float2 ml0 = pml[(size_t)bh * 2048 + q];
    float2 ml1 = pml[(size_t)(32 + bh) * 2048 + q];
    float M = fmaxf(ml0.x, ml1.x);
    float w0 = exp2_fast(ml0.x - M) * ml0.y;
    float w1 = exp2_fast(ml1.x - M) * ml1.y;
    float inv = 1.0f / (w0 + w1);
    w0 *= inv; w1 *= inv;
    half4v a = *(const half4v*)(po16 + ((size_t)bh * 2048 + q) * 64 + d4 * 4);
    half4v b2 = *(const half4v*)(po16 + ((size_t)(32 + bh) * 2048 + q) * 64 + d4 * 4);
    half4v o;
#pragma unroll
    for (int e = 0; e < 4; e++) o[e] = (half_t)((float)a[e] * w0 + (float)b2[e] * w1);
    int b = bh >> 4, h = bh & 15;
    *(half4v*)(aoh + ((size_t)b * 2048 + q) * 1024 + h * 64 + d4 * 4) = o;
}

// ---------------- proj GEMM: fp16, BK=64, + bias, f32 out ----------------
__global__ __launch_bounds__(256) void gemm_proj(
    const half_t* __restrict__ A, const half_t* __restrict__ Bt,
    const float* __restrict__ bias, float* __restrict__ out) {
    const int K = 1024;
    __shared__ __align__(16) half_t Al[128 * 64];
    __shared__ __align__(16) half_t Bl[128 * 64];
    int tid = threadIdx.x, w = tid >> 6, l = tid & 63;
    int wr = w >> 1, wc = w & 1, g = l >> 4, r = l & 15;
    int m0 = blockIdx.x * 128, n0 = blockIdx.y * 128;
    f32x4 acc[4][4] = {};

    for (int k0 = 0; k0 < K; k0 += 64) {
#pragma unroll
        for (int p = 0; p < 4; p++) {
            int ci = (p * 4 + w) * 64 + l;
            int row = ci >> 3, c = ci & 7;
            int lc = c ^ (row & 7);
            gl_lds16(A + (size_t)(m0 + row) * K + k0 + lc * 8, Al + (p * 4 + w) * 512);
            gl_lds16(Bt + (size_t)(n0 + row) * K + k0 + lc * 8, Bl + (p * 4 + w) * 512);
        }
        __syncthreads();
#pragma unroll
        for (int ks = 0; ks < 2; ks++) {
            half8 af[4], bf[4];
#pragma unroll
            for (int i = 0; i < 4; i++) {
                int row = wr * 64 + i * 16 + r;
                af[i] = *(const half8*)(Al + row * 64 + (((4 * ks + g) ^ (row & 7)) << 3));
                int rowb = wc * 64 + i * 16 + r;
                bf[i] = *(const half8*)(Bl + rowb * 64 + (((4 * ks + g) ^ (rowb & 7)) << 3));
            }
#pragma unroll
            for (int i = 0; i < 4; i++)
#pragma unroll
                for (int j = 0; j < 4; j++)
                    acc[i][j] = __builtin_amdgcn_mfma_f32_16x16x32_f16(af[i], bf[j], acc[i][j], 0, 0, 0);
        }
        __syncthreads();
    }

#pragma unroll
    for (int i = 0; i < 4; i++)
#pragma unroll
        for (int j = 0; j < 4; j++) {
            int gcol = n0 + wc * 64 + j * 16 + r;
            float bv = bias[gcol];
#pragma unroll
            for (int rr = 0; rr < 4; rr++) {
                int grow = m0 + wr * 64 + i * 16 + g * 4 + rr;
                out[(size_t)grow * 1024 + gcol] = acc[i][j][rr] + bv;
            }
        }
}

// ---------------- launch ----------------
extern "C" void kernel_launch(void* const* d_in, const int* in_sizes, int n_in,
                              void* d_out, int out_size, void* d_ws, size_t ws_size,
                              hipStream_t stream) {
    const float* x = (const float*)d_in[0];
    const float* Wqkv = (const float*)d_in[1];
    const float* Wproj = (const float*)d_in[2];
    const float* bproj = (const float*)d_in[3];
    const float* qscale = (const float*)d_in[4];
    const float* kscale = (const float*)d_in[5];
    float* out = (float*)d_out;

    char* ws = (char*)d_ws;
    // layout (51 MB total). po16 aliases xh+wqt (dead once attn runs).
    half_t* xh   = (half_t*)(ws + 0);          //  8 MB (4096x1024 fp16), dead after gemm_qkv
    half_t* wqt  = (half_t*)(ws + 8388608);    //  6 MB (3072x1024 fp16), dead after gemm_qkv
    half_t* po16 = (half_t*)(ws + 0);          // 16 MB [2][32][2048][64] fp16 partials (aliases xh/wqt)
    float2* pml  = (float2*)(ws + 16777216);   //  1 MB [2][32][2048] (m, lsum)
    half_t* qh   = (half_t*)(ws + 17825792);   //  8 MB (b,h,n,f)
    half_t* kh   = (half_t*)(ws + 26214400);   //  8 MB (b,h,n,f)
    half_t* vth  = (half_t*)(ws + 34603008);   //  8 MB (b,h,f,n)
    half_t* wpt  = (half_t*)(ws + 42991616);   //  2 MB (1024x1024 fp16, transposed)
    half_t* aoh  = (half_t*)(ws + 45088768);   //  8 MB (b,n,c)

    prep_all<<<8192, 256, 0, stream>>>(x, Wqkv, Wproj, xh, wqt, wpt);
    gemm_qkv<<<dim3(32, 24), 256, 0, stream>>>(xh, wqt, qscale, kscale, qh, kh, vth);
    attn<<<dim3(16, 32, 2), 512, 0, stream>>>(qh, kh, vth, po16, pml);
    attn_combine<<<4096, 256, 0, stream>>>(po16, pml, aoh);
    gemm_proj<<<dim3(32, 8), 256, 0, stream>>>(aoh, wpt, bproj, out);
}

// Round 13
// 133.887 us; speedup vs baseline: 1.3767x; 1.3767x over previous
//
#include <hip/hip_runtime.h>

// Problem constants: B=2, N=2048, C=1024, H=16, hd=64
// x:(2,2048,1024) f32; Wqkv:(1024,3072); Wproj:(1024,1024); bproj:(1024); q_scale,k_scale:(64)
// out:(2,2048,1024) f32

typedef _Float16 half_t;
typedef __attribute__((ext_vector_type(2))) __fp16 fp16x2;
typedef __attribute__((ext_vector_type(4))) _Float16 half4v;
typedef __attribute__((ext_vector_type(8))) _Float16 half8;
typedef __attribute__((ext_vector_type(4))) float f32x4;
typedef __attribute__((ext_vector_type(4))) unsigned uint4v;

#define DI __device__ __forceinline__

DI void gl_lds16(const void* g, void* l) {
    __builtin_amdgcn_global_load_lds((const __attribute__((address_space(1))) void*)g,
                                     (__attribute__((address_space(3))) void*)l, 16, 0, 0);
}

DI float exp2_fast(float x) {
    float r;
    asm("v_exp_f32 %0, %1" : "=v"(r) : "v"(x));
    return r;
}

// v_permlane32_swap_b32: a.rows[2,3] <-> b.rows[0,1] (rows = 16-lane groups)
DI void pl32_swap(unsigned& a, unsigned& b) {
    asm("v_permlane32_swap_b32 %0, %1" : "+v"(a), "+v"(b));
}
// v_permlane16_swap_b32: a.rows[1,3] <-> b.rows[0,2]
DI void pl16_swap(unsigned& a, unsigned& b) {
    asm("v_permlane16_swap_b32 %0, %1" : "+v"(a), "+v"(b));
}

DI unsigned pk_u32(float lo, float hi) {
    fp16x2 t = __builtin_amdgcn_cvt_pkrtz(lo, hi);
    return *(unsigned*)&t;
}

// ---------------- merged prep kernel ----------------
// blocks [0,4096): x f32->fp16 ; [4096,7168): Wqkv transpose->fp16 ; [7168,8192): Wproj
__global__ void prep_all(const float* __restrict__ x, const float* __restrict__ Wqkv,
                         const float* __restrict__ Wproj, half_t* __restrict__ xh,
                         half_t* __restrict__ wqt, half_t* __restrict__ wpt) {
    __shared__ float t[32][33];
    int bid = blockIdx.x;
    if (bid < 4096) {
        int i = (bid * 256 + threadIdx.x) * 4;
        float4 v = *(const float4*)(x + i);
        half4v o;
        o[0] = (half_t)v.x; o[1] = (half_t)v.y; o[2] = (half_t)v.z; o[3] = (half_t)v.w;
        *(half4v*)(xh + i) = o;
    } else if (bid < 4096 + 3072) {
        int i = bid - 4096;
        int c0 = (i % 96) * 32, r0 = (i / 96) * 32;
        int tx = threadIdx.x & 31, ty = threadIdx.x >> 5;
#pragma unroll
        for (int k = 0; k < 4; k++)
            t[ty + 8 * k][tx] = Wqkv[(size_t)(r0 + ty + 8 * k) * 3072 + c0 + tx];
        __syncthreads();
#pragma unroll
        for (int k = 0; k < 4; k++)
            wqt[(size_t)(c0 + ty + 8 * k) * 1024 + r0 + tx] = (half_t)t[tx][ty + 8 * k];
    } else {
        int i = bid - 4096 - 3072;
        int c0 = (i % 32) * 32, r0 = (i / 32) * 32;
        int tx = threadIdx.x & 31, ty = threadIdx.x >> 5;
#pragma unroll
        for (int k = 0; k < 4; k++)
            t[ty + 8 * k][tx] = Wproj[(size_t)(r0 + ty + 8 * k) * 1024 + c0 + tx];
        __syncthreads();
#pragma unroll
        for (int k = 0; k < 4; k++)
            wpt[(size_t)(c0 + ty + 8 * k) * 1024 + r0 + tx] = (half_t)t[tx][ty + 8 * k];
    }
}

// ---------------- QKV GEMM: fp16, BK=64, dbuf LDS, fused RMSNorm epilogue ----------------
__global__ __launch_bounds__(256) void gemm_qkv(
    const half_t* __restrict__ A, const half_t* __restrict__ Bt,
    const float* __restrict__ qs, const float* __restrict__ ks,
    half_t* __restrict__ qh, half_t* __restrict__ kh, half_t* __restrict__ vth) {
    const int K = 1024;
    __shared__ __align__(16) half_t Al[2][128 * 64];
    __shared__ __align__(16) half_t Bl[2][128 * 64];
    int tid = threadIdx.x;
    int w = tid >> 6, l = tid & 63;
    int wr = w >> 1, wc = w & 1;
    int g = l >> 4, r = l & 15;
    int m0 = blockIdx.x * 128, n0 = blockIdx.y * 128;
    f32x4 acc[4][4] = {};

#define STAGE_QKV(kt, buf)                                                        \
    {                                                                             \
        _Pragma("unroll")                                                         \
        for (int p = 0; p < 4; p++) {                                             \
            int ci = p * 256 + tid;                                               \
            int row = ci >> 3, c = ci & 7, lc = c ^ (row & 7);                    \
            gl_lds16(A + (size_t)(m0 + row) * K + (kt) * 64 + lc * 8,             \
                     &Al[buf][0] + ci * 8);                                       \
            gl_lds16(Bt + (size_t)(n0 + row) * K + (kt) * 64 + lc * 8,            \
                     &Bl[buf][0] + ci * 8);                                       \
        }                                                                         \
    }

    STAGE_QKV(0, 0);
    __syncthreads();
    int cur = 0;
    for (int kt = 0; kt < 16; kt++) {
        if (kt < 15) STAGE_QKV(kt + 1, cur ^ 1);
#pragma unroll
        for (int ks2 = 0; ks2 < 2; ks2++) {
            half8 af[4], bf[4];
#pragma unroll
            for (int i = 0; i < 4; i++) {
                int row = wr * 64 + i * 16 + r;
                af[i] = *(const half8*)(&Al[cur][0] + row * 64 + (((4 * ks2 + g) ^ (row & 7)) << 3));
                int rowb = wc * 64 + i * 16 + r;
                bf[i] = *(const half8*)(&Bl[cur][0] + rowb * 64 + (((4 * ks2 + g) ^ (rowb & 7)) << 3));
            }
#pragma unroll
            for (int i = 0; i < 4; i++)
#pragma unroll
                for (int j = 0; j < 4; j++)
                    acc[i][j] = __builtin_amdgcn_mfma_f32_16x16x32_f16(af[i], bf[j], acc[i][j], 0, 0, 0);
        }
        __syncthreads();
        cur ^= 1;
    }

    int tsec = n0 >> 10;  // 0=q, 1=k, 2=v (uniform per block)
    if (tsec == 2) {
#pragma unroll
        for (int i = 0; i < 4; i++)
#pragma unroll
            for (int j = 0; j < 4; j++) {
                int gcol = n0 + wc * 64 + j * 16 + r;
                int h = (gcol >> 6) & 15;
                int f = gcol & 63;
                int growb = m0 + wr * 64 + i * 16 + g * 4;
                int b = growb >> 11;
                int n = growb & 2047;
                half4v pv;
#pragma unroll
                for (int rr = 0; rr < 4; rr++) pv[rr] = (half_t)acc[i][j][rr];
                *(half4v*)(vth + ((size_t)(b * 16 + h) * 64 + f) * 2048 + n) = pv;
            }
    } else {
        const float* sc = (tsec == 0) ? qs : ks;
        half_t* dst = (tsec == 0) ? qh : kh;
        float extra = (tsec == 0) ? (0.125f * 1.44269504f) : 1.0f;  // fold hd^-0.5*log2e into q
        float scv[4];
#pragma unroll
        for (int j = 0; j < 4; j++) scv[j] = sc[j * 16 + r];
#pragma unroll
        for (int i = 0; i < 4; i++)
#pragma unroll
            for (int rr = 0; rr < 4; rr++) {
                float ss = 0.f;
#pragma unroll
                for (int j = 0; j < 4; j++) ss += acc[i][j][rr] * acc[i][j][rr];
#pragma unroll
                for (int d = 1; d < 16; d <<= 1) ss += __shfl_xor(ss, d, 64);
                float inv = extra / (sqrtf(ss) * 0.125f + 1e-8f);  // rms = ||row||/8
                int grow = m0 + wr * 64 + i * 16 + g * 4 + rr;
                int b = grow >> 11;
                int n = grow & 2047;
#pragma unroll
                for (int j = 0; j < 4; j++) {
                    int gcol = n0 + wc * 64 + j * 16 + r;
                    int h = (gcol >> 6) & 15;
                    int f = gcol & 63;
                    dst[((size_t)(b * 16 + h) * 2048 + n) * 64 + f] =
                        (half_t)(acc[i][j][rr] * inv * scv[j]);
                }
            }
    }
}

// ---------------- flash attention: IN-BLOCK kv-split-2, 32 waves/CU ----------------
// grid (32 q-tiles, 32 bh) = 1024 blocks x 8 waves = 32 waves/CU (slot max).
// Waves 0-3 process kv [0,1024), waves 4-7 kv [1024,2048), SAME 64 q-rows.
// KVBLK=32 double-buffered per half -> 32KB LDS/block -> 4 blocks/CU.
// launch_bounds(512,8) caps VGPR at 64 (R12's identical loop compiled at 32).
// NO global partials (R12's 213MB-fetch poison): halves merge via LDS in f32,
// half0 writes aoh. Split-softmax merge is exact for deferred maxima.
// Permlane PV (R10-verified), predicate defer-max THR=11 (PROVEN numerics).
__global__ __launch_bounds__(512, 8) void attn(
    const half_t* __restrict__ qh, const half_t* __restrict__ kh,
    const half_t* __restrict__ vth, half_t* __restrict__ aoh) {
    int bh = blockIdx.y;
    int q0 = blockIdx.x * 64;
    int tid = threadIdx.x, w = tid >> 6, l = tid & 63, g = l >> 4, r = l & 15;
    int hf = w >> 2, qs = w & 3, lt = tid & 255;

    const half_t* Qp = qh + (size_t)bh * 2048 * 64;
    const half_t* Kp = kh + (size_t)bh * 2048 * 64 + (size_t)hf * 1024 * 64;
    const half_t* Vp = vth + (size_t)bh * 64 * 2048 + hf * 1024;  // (feat, n)

    // 32KB shared: [0,16K) = K buffers (half0 dbuf, half1 dbuf), [16K,32K) = V buffers.
    // Reused as f32 merge area after the final loop barrier.
    __shared__ __align__(16) char smem[32768];
    half_t* Kb[2] = {(half_t*)(smem + hf * 8192), (half_t*)(smem + hf * 8192 + 4096)};
    half_t* Vb[2] = {(half_t*)(smem + 16384 + hf * 8192), (half_t*)(smem + 16384 + hf * 8192 + 4096)};

    // staging (256 thr per half, 1 K-chunk + 1 V-chunk of 16B each per tile)
    // K tile: 32 rows(kv) x 64(hd): 8 chunks/row, XOR c^(row&7)
    int krow = lt >> 3, kc = lt & 7, klc = kc ^ (krow & 7);
    const half_t* kst = Kp + (size_t)krow * 64 + klc * 8;
    // V tile: 64 rows(feat) x 32(kv): 4 chunks/row, XOR c^((row>>1)&3)
    int vrow = lt >> 2, vc = lt & 3, vlc = vc ^ ((vrow >> 1) & 3);
    const half_t* vst = Vp + (size_t)vrow * 2048 + vlc * 8;

    // hoisted LDS read offsets
    int koff[4], voff[4];
#pragma unroll
    for (int ks = 0; ks < 2; ks++)
#pragma unroll
        for (int tt = 0; tt < 2; tt++) {
            int row = tt * 16 + r;
            koff[ks * 2 + tt] = row * 64 + (((ks * 4 + g) ^ (row & 7)) << 3);
        }
#pragma unroll
    for (int cf = 0; cf < 4; cf++) {
        int row = cf * 16 + r;
        voff[cf] = row * 32 + ((g ^ ((row >> 1) & 3)) << 3);
    }

    // Q fragment: Q[q = q0 + qs*16 + r][hd = 32ks + 8g + e]
    half8 qf[2];
#pragma unroll
    for (int ks = 0; ks < 2; ks++)
        qf[ks] = *(const half8*)(Qp + (size_t)(q0 + qs * 16 + r) * 64 + ks * 32 + g * 8);

    f32x4 o[4] = {};          // O^T[d = 16cf + 4g + reg][q = r] (this half's partial)
    float m = -1e30f, lsum = 0.f;

    // prologue: stage tile 0
    gl_lds16(kst, Kb[0] + lt * 8);
    gl_lds16(vst, Vb[0] + lt * 8);
    __syncthreads();

#define ATTN_TILE(BUF, T)                                                          \
    {                                                                              \
        if ((T) < 31) {                                                            \
            gl_lds16(kst + ((T) + 1) * 2048, Kb[(BUF) ^ 1] + lt * 8);              \
            gl_lds16(vst + ((T) + 1) * 32, Vb[(BUF) ^ 1] + lt * 8);                \
        }                                                                          \
        const half_t* Kc = Kb[BUF];                                                \
        const half_t* Vc = Vb[BUF];                                                \
        f32x4 s[2] = {};                                                           \
        _Pragma("unroll")                                                          \
        for (int ks = 0; ks < 2; ks++)                                             \
            _Pragma("unroll")                                                      \
            for (int tt = 0; tt < 2; tt++) {                                       \
                half8 kf = *(const half8*)(Kc + koff[ks * 2 + tt]);                \
                s[tt] = __builtin_amdgcn_mfma_f32_16x16x32_f16(kf, qf[ks], s[tt], 0, 0, 0); \
            }                                                                      \
        float thr = m + 11.0f;                                                     \
        bool ok = true;                                                            \
        _Pragma("unroll")                                                          \
        for (int tt = 0; tt < 2; tt++)                                             \
            _Pragma("unroll")                                                      \
            for (int e = 0; e < 4; e++) ok = ok && (s[tt][e] <= thr);              \
        if (!__all(ok)) {                                                          \
            float mx = fmaxf(fmaxf(s[0][0], s[0][1]), fmaxf(s[0][2], s[0][3]));    \
            mx = fmaxf(mx, fmaxf(fmaxf(s[1][0], s[1][1]), fmaxf(s[1][2], s[1][3]))); \
            mx = fmaxf(mx, __shfl_xor(mx, 16, 64));                                \
            mx = fmaxf(mx, __shfl_xor(mx, 32, 64));                                \
            float mn = fmaxf(m, mx);                                               \
            float fac = exp2_fast(m - mn);                                         \
            lsum *= fac;                                                           \
            _Pragma("unroll")                                                      \
            for (int cf = 0; cf < 4; cf++) {                                       \
                o[cf][0] *= fac; o[cf][1] *= fac; o[cf][2] *= fac; o[cf][3] *= fac; \
            }                                                                      \
            m = mn;                                                                \
        }                                                                          \
        _Pragma("unroll")                                                          \
        for (int tt = 0; tt < 2; tt++)                                             \
            _Pragma("unroll")                                                      \
            for (int e = 0; e < 4; e++) {                                          \
                float p = exp2_fast(s[tt][e] - m);                                 \
                s[tt][e] = p;                                                      \
                lsum += p;                                                         \
            }                                                                      \
        unsigned b0 = pk_u32(s[0][0], s[0][1]);                                    \
        unsigned b1 = pk_u32(s[0][2], s[0][3]);                                    \
        unsigned b2 = pk_u32(s[1][0], s[1][1]);                                    \
        unsigned b3 = pk_u32(s[1][2], s[1][3]);                                    \
        pl32_swap(b0, b2); pl16_swap(b0, b2);                                      \
        pl32_swap(b1, b3); pl16_swap(b1, b3);                                      \
        uint4v pw; pw[0] = b0; pw[1] = b1; pw[2] = b2; pw[3] = b3;                 \
        half8 pf = *(half8*)&pw;                                                   \
        _Pragma("unroll")                                                          \
        for (int cf = 0; cf < 4; cf++) {                                           \
            half8 vf = *(const half8*)(Vc + voff[cf]);                             \
            o[cf] = __builtin_amdgcn_mfma_f32_16x16x32_f16(vf, pf, o[cf], 0, 0, 0); \
        }                                                                          \
        __syncthreads();                                                           \
    }

    for (int t = 0; t < 32; t += 2) {
        ATTN_TILE(0, t);
        ATTN_TILE(1, t + 1);
    }
    // final barrier of the loop guarantees all K/V reads done -> smem reusable

    // g-group lsum reduction (lanes r, r+16, r+32, r+48 hold disjoint kv-slots)
    lsum += __shfl_xor(lsum, 16, 64);
    lsum += __shfl_xor(lsum, 32, 64);

    // merge the two kv-halves via LDS (f32, exact split-softmax algebra)
    float* mo = (float*)smem;             // [64 q][68] padded f32
    float* mml = (float*)(smem + 17408);  // [64 q][2] (m, ls)
    int q2 = qs * 16 + r;
    if (hf) {
#pragma unroll
        for (int cf = 0; cf < 4; cf++)
            *(f32x4*)(mo + q2 * 68 + cf * 16 + g * 4) = o[cf];
        if (l < 16) {
            mml[q2 * 2] = m;
            mml[q2 * 2 + 1] = lsum;
        }
    }
    __syncthreads();
    if (!hf) {
        float m1 = mml[q2 * 2], ls1 = mml[q2 * 2 + 1];
        float M = fmaxf(m, m1);
        float w0 = exp2_fast(m - M), w1 = exp2_fast(m1 - M);
        float inv = 1.0f / (w0 * lsum + w1 * ls1);
        w0 *= inv; w1 *= inv;
        int n = q0 + q2;
        int b = bh >> 4, h = bh & 15;
#pragma unroll
        for (int cf = 0; cf < 4; cf++) {
            f32x4 o1 = *(const f32x4*)(mo + q2 * 68 + cf * 16 + g * 4);
            half4v ov;
#pragma unroll
            for (int e = 0; e < 4; e++) ov[e] = (half_t)(o[cf][e] * w0 + o1[e] * w1);
            *(half4v*)(aoh + ((size_t)b * 2048 + n) * 1024 + h * 64 + cf * 16 + g * 4) = ov;
        }
    }
}

// ---------------- proj GEMM: fp16, BK=64, + bias, f32 out ----------------
__global__ __launch_bounds__(256) void gemm_proj(
    const half_t* __restrict__ A, const half_t* __restrict__ Bt,
    const float* __restrict__ bias, float* __restrict__ out) {
    const int K = 1024;
    __shared__ __align__(16) half_t Al[128 * 64];
    __shared__ __align__(16) half_t Bl[128 * 64];
    int tid = threadIdx.x, w = tid >> 6, l = tid & 63;
    int wr = w >> 1, wc = w & 1, g = l >> 4, r = l & 15;
    int m0 = blockIdx.x * 128, n0 = blockIdx.y * 128;
    f32x4 acc[4][4] = {};

    for (int k0 = 0; k0 < K; k0 += 64) {
#pragma unroll
        for (int p = 0; p < 4; p++) {
            int ci = (p * 4 + w) * 64 + l;
            int row = ci >> 3, c = ci & 7;
            int lc = c ^ (row & 7);
            gl_lds16(A + (size_t)(m0 + row) * K + k0 + lc * 8, Al + (p * 4 + w) * 512);
            gl_lds16(Bt + (size_t)(n0 + row) * K + k0 + lc * 8, Bl + (p * 4 + w) * 512);
        }
        __syncthreads();
#pragma unroll
        for (int ks = 0; ks < 2; ks++) {
            half8 af[4], bf[4];
#pragma unroll
            for (int i = 0; i < 4; i++) {
                int row = wr * 64 + i * 16 + r;
                af[i] = *(const half8*)(Al + row * 64 + (((4 * ks + g) ^ (row & 7)) << 3));
                int rowb = wc * 64 + i * 16 + r;
                bf[i] = *(const half8*)(Bl + rowb * 64 + (((4 * ks + g) ^ (rowb & 7)) << 3));
            }
#pragma unroll
            for (int i = 0; i < 4; i++)
#pragma unroll
                for (int j = 0; j < 4; j++)
                    acc[i][j] = __builtin_amdgcn_mfma_f32_16x16x32_f16(af[i], bf[j], acc[i][j], 0, 0, 0);
        }
        __syncthreads();
    }

#pragma unroll
    for (int i = 0; i < 4; i++)
#pragma unroll
        for (int j = 0; j < 4; j++) {
            int gcol = n0 + wc * 64 + j * 16 + r;
            float bv = bias[gcol];
#pragma unroll
            for (int rr = 0; rr < 4; rr++) {
                int grow = m0 + wr * 64 + i * 16 + g * 4 + rr;
                out[(size_t)grow * 1024 + gcol] = acc[i][j][rr] + bv;
            }
        }
}

// ---------------- launch ----------------
extern "C" void kernel_launch(void* const* d_in, const int* in_sizes, int n_in,
                              void* d_out, int out_size, void* d_ws, size_t ws_size,
                              hipStream_t stream) {
    const float* x = (const float*)d_in[0];
    const float* Wqkv = (const float*)d_in[1];
    const float* Wproj = (const float*)d_in[2];
    const float* bproj = (const float*)d_in[3];
    const float* qscale = (const float*)d_in[4];
    const float* kscale = (const float*)d_in[5];
    float* out = (float*)d_out;

    char* ws = (char*)d_ws;
    half_t* xh  = (half_t*)(ws + 0);         //  8.0 MB (4096 x 1024 fp16)
    half_t* wqt = (half_t*)(ws + 8388608);   //  6.0 MB (3072 x 1024 fp16, transposed)
    half_t* wpt = (half_t*)(ws + 14680064);  //  2.0 MB (1024 x 1024 fp16, transposed)
    half_t* qh  = (half_t*)(ws + 16777216);  //  8.0 MB (b,h,n,f)
    half_t* kh  = (half_t*)(ws + 25165824);  //  8.0 MB (b,h,n,f)
    half_t* vth = (half_t*)(ws + 33554432);  //  8.0 MB (b,h,f,n)
    half_t* aoh = (half_t*)(ws + 41943040);  //  8.0 MB (b,n,c)

    prep_all<<<8192, 256, 0, stream>>>(x, Wqkv, Wproj, xh, wqt, wpt);
    gemm_qkv<<<dim3(32, 24), 256, 0, stream>>>(xh, wqt, qscale, kscale, qh, kh, vth);
    attn<<<dim3(32, 32), 512, 0, stream>>>(qh, kh, vth, aoh);
    gemm_proj<<<dim3(32, 8), 256, 0, stream>>>(aoh, wpt, bproj, out);
}

// Round 15
// 124.906 us; speedup vs baseline: 1.4756x; 1.0719x over previous
//
#include <hip/hip_runtime.h>

// Problem constants: B=2, N=2048, C=1024, H=16, hd=64
// x:(2,2048,1024) f32; Wqkv:(1024,3072); Wproj:(1024,1024); bproj:(1024); q_scale,k_scale:(64)
// out:(2,2048,1024) f32

typedef _Float16 half_t;
typedef __attribute__((ext_vector_type(2))) __fp16 fp16x2;
typedef __attribute__((ext_vector_type(4))) _Float16 half4v;
typedef __attribute__((ext_vector_type(8))) _Float16 half8;
typedef __attribute__((ext_vector_type(4))) float f32x4;
typedef __attribute__((ext_vector_type(4))) unsigned uint4v;

#define DI __device__ __forceinline__

DI void gl_lds16(const void* g, void* l) {
    __builtin_amdgcn_global_load_lds((const __attribute__((address_space(1))) void*)g,
                                     (__attribute__((address_space(3))) void*)l, 16, 0, 0);
}

DI float exp2_fast(float x) {
    float r;
    asm("v_exp_f32 %0, %1" : "=v"(r) : "v"(x));
    return r;
}

// v_permlane32_swap_b32: a.rows[2,3] <-> b.rows[0,1] (rows = 16-lane groups)
DI void pl32_swap(unsigned& a, unsigned& b) {
    asm("v_permlane32_swap_b32 %0, %1" : "+v"(a), "+v"(b));
}
// v_permlane16_swap_b32: a.rows[1,3] <-> b.rows[0,2]
DI void pl16_swap(unsigned& a, unsigned& b) {
    asm("v_permlane16_swap_b32 %0, %1" : "+v"(a), "+v"(b));
}

DI unsigned pk_u32(float lo, float hi) {
    fp16x2 t = __builtin_amdgcn_cvt_pkrtz(lo, hi);
    return *(unsigned*)&t;
}

// ---------------- merged prep kernel ----------------
// blocks [0,4096): x f32->fp16 ; [4096,7168): Wqkv transpose->fp16 ; [7168,8192): Wproj
__global__ void prep_all(const float* __restrict__ x, const float* __restrict__ Wqkv,
                         const float* __restrict__ Wproj, half_t* __restrict__ xh,
                         half_t* __restrict__ wqt, half_t* __restrict__ wpt) {
    __shared__ float t[32][33];
    int bid = blockIdx.x;
    if (bid < 4096) {
        int i = (bid * 256 + threadIdx.x) * 4;
        float4 v = *(const float4*)(x + i);
        half4v o;
        o[0] = (half_t)v.x; o[1] = (half_t)v.y; o[2] = (half_t)v.z; o[3] = (half_t)v.w;
        *(half4v*)(xh + i) = o;
    } else if (bid < 4096 + 3072) {
        int i = bid - 4096;
        int c0 = (i % 96) * 32, r0 = (i / 96) * 32;
        int tx = threadIdx.x & 31, ty = threadIdx.x >> 5;
#pragma unroll
        for (int k = 0; k < 4; k++)
            t[ty + 8 * k][tx] = Wqkv[(size_t)(r0 + ty + 8 * k) * 3072 + c0 + tx];
        __syncthreads();
#pragma unroll
        for (int k = 0; k < 4; k++)
            wqt[(size_t)(c0 + ty + 8 * k) * 1024 + r0 + tx] = (half_t)t[tx][ty + 8 * k];
    } else {
        int i = bid - 4096 - 3072;
        int c0 = (i % 32) * 32, r0 = (i / 32) * 32;
        int tx = threadIdx.x & 31, ty = threadIdx.x >> 5;
#pragma unroll
        for (int k = 0; k < 4; k++)
            t[ty + 8 * k][tx] = Wproj[(size_t)(r0 + ty + 8 * k) * 1024 + c0 + tx];
        __syncthreads();
#pragma unroll
        for (int k = 0; k < 4; k++)
            wpt[(size_t)(c0 + ty + 8 * k) * 1024 + r0 + tx] = (half_t)t[tx][ty + 8 * k];
    }
}

// ---------------- QKV GEMM: fp16, BK=32, dbuf LDS (32KB -> ~5 blocks/CU) ------------
// Occupancy fix (same thesis as the R13 attn win): BK=64's 64KB LDS capped this
// kernel at 2 blocks/CU (15.7% occupancy, MfmaUtil 31.7%). BK=32 dbuf = 32KB ->
// ~5 blocks/CU (20 waves/CU). Rows are 4 chunks of 16B; stage/read swizzle
// c ^ ((row>>1)&3) (XOR involution both sides); read = 2-way bank alias (free).
// Fused RMSNorm epilogue unchanged (q/k from f32 acc; v stored transposed).
__global__ __launch_bounds__(256, 4) void gemm_qkv(
    const half_t* __restrict__ A, const half_t* __restrict__ Bt,
    const float* __restrict__ qs, const float* __restrict__ ks,
    half_t* __restrict__ qh, half_t* __restrict__ kh, half_t* __restrict__ vth) {
    const int K = 1024;
    __shared__ __align__(16) half_t Al[2][128 * 32];
    __shared__ __align__(16) half_t Bl[2][128 * 32];
    int tid = threadIdx.x;
    int w = tid >> 6, l = tid & 63;
    int wr = w >> 1, wc = w & 1;
    int g = l >> 4, r = l & 15;
    int m0 = blockIdx.x * 128, n0 = blockIdx.y * 128;
    f32x4 acc[4][4] = {};

#define STAGE_QKV(kt, buf)                                                        \
    {                                                                             \
        _Pragma("unroll")                                                         \
        for (int p = 0; p < 2; p++) {                                             \
            int ci = p * 256 + tid;                                               \
            int row = ci >> 2, c = ci & 3, lc = c ^ ((row >> 1) & 3);             \
            gl_lds16(A + (size_t)(m0 + row) * K + (kt) * 32 + lc * 8,             \
                     &Al[buf][0] + ci * 8);                                       \
            gl_lds16(Bt + (size_t)(n0 + row) * K + (kt) * 32 + lc * 8,            \
                     &Bl[buf][0] + ci * 8);                                       \
        }                                                                         \
    }

    STAGE_QKV(0, 0);
    __syncthreads();
    int cur = 0;
    for (int kt = 0; kt < 32; kt++) {
        if (kt < 31) STAGE_QKV(kt + 1, cur ^ 1);
        half8 af[4], bf[4];
#pragma unroll
        for (int i = 0; i < 4; i++) {
            int row = wr * 64 + i * 16 + r;
            af[i] = *(const half8*)(&Al[cur][0] + row * 32 + ((g ^ ((row >> 1) & 3)) << 3));
            int rowb = wc * 64 + i * 16 + r;
            bf[i] = *(const half8*)(&Bl[cur][0] + rowb * 32 + ((g ^ ((rowb >> 1) & 3)) << 3));
        }
#pragma unroll
        for (int i = 0; i < 4; i++)
#pragma unroll
            for (int j = 0; j < 4; j++)
                acc[i][j] = __builtin_amdgcn_mfma_f32_16x16x32_f16(af[i], bf[j], acc[i][j], 0, 0, 0);
        __syncthreads();
        cur ^= 1;
    }

    int tsec = n0 >> 10;  // 0=q, 1=k, 2=v (uniform per block)
    if (tsec == 2) {
#pragma unroll
        for (int i = 0; i < 4; i++)
#pragma unroll
            for (int j = 0; j < 4; j++) {
                int gcol = n0 + wc * 64 + j * 16 + r;
                int h = (gcol >> 6) & 15;
                int f = gcol & 63;
                int growb = m0 + wr * 64 + i * 16 + g * 4;
                int b = growb >> 11;
                int n = growb & 2047;
                half4v pv;
#pragma unroll
                for (int rr = 0; rr < 4; rr++) pv[rr] = (half_t)acc[i][j][rr];
                *(half4v*)(vth + ((size_t)(b * 16 + h) * 64 + f) * 2048 + n) = pv;
            }
    } else {
        const float* sc = (tsec == 0) ? qs : ks;
        half_t* dst = (tsec == 0) ? qh : kh;
        float extra = (tsec == 0) ? (0.125f * 1.44269504f) : 1.0f;  // fold hd^-0.5*log2e into q
        float scv[4];
#pragma unroll
        for (int j = 0; j < 4; j++) scv[j] = sc[j * 16 + r];
#pragma unroll
        for (int i = 0; i < 4; i++)
#pragma unroll
            for (int rr = 0; rr < 4; rr++) {
                float ss = 0.f;
#pragma unroll
                for (int j = 0; j < 4; j++) ss += acc[i][j][rr] * acc[i][j][rr];
#pragma unroll
                for (int d = 1; d < 16; d <<= 1) ss += __shfl_xor(ss, d, 64);
                float inv = extra / (sqrtf(ss) * 0.125f + 1e-8f);  // rms = ||row||/8
                int grow = m0 + wr * 64 + i * 16 + g * 4 + rr;
                int b = grow >> 11;
                int n = grow & 2047;
#pragma unroll
                for (int j = 0; j < 4; j++) {
                    int gcol = n0 + wc * 64 + j * 16 + r;
                    int h = (gcol >> 6) & 15;
                    int f = gcol & 63;
                    dst[((size_t)(b * 16 + h) * 2048 + n) * 64 + f] =
                        (half_t)(acc[i][j][rr] * inv * scv[j]);
                }
            }
    }
}

// ---------------- flash attention: IN-BLOCK kv-split-2, 32 waves/CU ----------------
// EXACT R13 kernel (proven pass, 56.5us). R14's ones-MFMA lsum failed numerically
// (5.1e-2, like R6's no-max 4.7e-2) — lsum MUST be the per-element f32 sum.
// grid (32 q-tiles, 32 bh) = 1024 blocks x 8 waves = 32 waves/CU (slot max).
// Waves 0-3 kv [0,1024), waves 4-7 kv [1024,2048), same 64 q-rows; LDS f32 merge.
// Permlane PV (R10-verified), predicate defer-max THR=11 (PROVEN numerics).
__global__ __launch_bounds__(512, 8) void attn(
    const half_t* __restrict__ qh, const half_t* __restrict__ kh,
    const half_t* __restrict__ vth, half_t* __restrict__ aoh) {
    int bh = blockIdx.y;
    int q0 = blockIdx.x * 64;
    int tid = threadIdx.x, w = tid >> 6, l = tid & 63, g = l >> 4, r = l & 15;
    int hf = w >> 2, qs = w & 3, lt = tid & 255;

    const half_t* Qp = qh + (size_t)bh * 2048 * 64;
    const half_t* Kp = kh + (size_t)bh * 2048 * 64 + (size_t)hf * 1024 * 64;
    const half_t* Vp = vth + (size_t)bh * 64 * 2048 + hf * 1024;  // (feat, n)

    // 32KB shared: [0,16K) = K buffers (per-half dbuf), [16K,32K) = V buffers.
    // Reused as f32 merge area after the final loop barrier.
    __shared__ __align__(16) char smem[32768];
    half_t* Kb[2] = {(half_t*)(smem + hf * 8192), (half_t*)(smem + hf * 8192 + 4096)};
    half_t* Vb[2] = {(half_t*)(smem + 16384 + hf * 8192), (half_t*)(smem + 16384 + hf * 8192 + 4096)};

    // staging (256 thr per half, 1 K-chunk + 1 V-chunk of 16B each per tile)
    int krow = lt >> 3, kc = lt & 7, klc = kc ^ (krow & 7);
    const half_t* kst = Kp + (size_t)krow * 64 + klc * 8;
    int vrow = lt >> 2, vc = lt & 3, vlc = vc ^ ((vrow >> 1) & 3);
    const half_t* vst = Vp + (size_t)vrow * 2048 + vlc * 8;

    // hoisted LDS read offsets
    int koff[4], voff[4];
#pragma unroll
    for (int ks = 0; ks < 2; ks++)
#pragma unroll
        for (int tt = 0; tt < 2; tt++) {
            int row = tt * 16 + r;
            koff[ks * 2 + tt] = row * 64 + (((ks * 4 + g) ^ (row & 7)) << 3);
        }
#pragma unroll
    for (int cf = 0; cf < 4; cf++) {
        int row = cf * 16 + r;
        voff[cf] = row * 32 + ((g ^ ((row >> 1) & 3)) << 3);
    }

    // Q fragment: Q[q = q0 + qs*16 + r][hd = 32ks + 8g + e]
    half8 qf[2];
#pragma unroll
    for (int ks = 0; ks < 2; ks++)
        qf[ks] = *(const half8*)(Qp + (size_t)(q0 + qs * 16 + r) * 64 + ks * 32 + g * 8);

    f32x4 o[4] = {};          // O^T[d = 16cf + 4g + reg][q = r] (this half's partial)
    float m = -1e30f, lsum = 0.f;

    // prologue: stage tile 0
    gl_lds16(kst, Kb[0] + lt * 8);
    gl_lds16(vst, Vb[0] + lt * 8);
    __syncthreads();

#define ATTN_TILE(BUF, T)                                                          \
    {                                                                              \
        if ((T) < 31) {                                                            \
            gl_lds16(kst + ((T) + 1) * 2048, Kb[(BUF) ^ 1] + lt * 8);              \
            gl_lds16(vst + ((T) + 1) * 32, Vb[(BUF) ^ 1] + lt * 8);                \
        }                                                                          \
        const half_t* Kc = Kb[BUF];                                                \
        const half_t* Vc = Vb[BUF];                                                \
        f32x4 s[2] = {};                                                           \
        _Pragma("unroll")                                                          \
        for (int ks = 0; ks < 2; ks++)                                             \
            _Pragma("unroll")                                                      \
            for (int tt = 0; tt < 2; tt++) {                                       \
                half8 kf = *(const half8*)(Kc + koff[ks * 2 + tt]);                \
                s[tt] = __builtin_amdgcn_mfma_f32_16x16x32_f16(kf, qf[ks], s[tt], 0, 0, 0); \
            }                                                                      \
        float thr = m + 11.0f;                                                     \
        bool ok = true;                                                            \
        _Pragma("unroll")                                                          \
        for (int tt = 0; tt < 2; tt++)                                             \
            _Pragma("unroll")                                                      \
            for (int e = 0; e < 4; e++) ok = ok && (s[tt][e] <= thr);              \
        if (!__all(ok)) {                                                          \
            float mx = fmaxf(fmaxf(s[0][0], s[0][1]), fmaxf(s[0][2], s[0][3]));    \
            mx = fmaxf(mx, fmaxf(fmaxf(s[1][0], s[1][1]), fmaxf(s[1][2], s[1][3]))); \
            mx = fmaxf(mx, __shfl_xor(mx, 16, 64));                                \
            mx = fmaxf(mx, __shfl_xor(mx, 32, 64));                                \
            float mn = fmaxf(m, mx);                                               \
            float fac = exp2_fast(m - mn);                                         \
            lsum *= fac;                                                           \
            _Pragma("unroll")                                                      \
            for (int cf = 0; cf < 4; cf++) {                                       \
                o[cf][0] *= fac; o[cf][1] *= fac; o[cf][2] *= fac; o[cf][3] *= fac; \
            }                                                                      \
            m = mn;                                                                \
        }                                                                          \
        _Pragma("unroll")                                                          \
        for (int tt = 0; tt < 2; tt++)                                             \
            _Pragma("unroll")                                                      \
            for (int e = 0; e < 4; e++) {                                          \
                float p = exp2_fast(s[tt][e] - m);                                 \
                s[tt][e] = p;                                                      \
                lsum += p;                                                         \
            }                                                                      \
        unsigned b0 = pk_u32(s[0][0], s[0][1]);                                    \
        unsigned b1 = pk_u32(s[0][2], s[0][3]);                                    \
        unsigned b2 = pk_u32(s[1][0], s[1][1]);                                    \
        unsigned b3 = pk_u32(s[1][2], s[1][3]);                                    \
        pl32_swap(b0, b2); pl16_swap(b0, b2);                                      \
        pl32_swap(b1, b3); pl16_swap(b1, b3);                                      \
        uint4v pw; pw[0] = b0; pw[1] = b1; pw[2] = b2; pw[3] = b3;                 \
        half8 pf = *(half8*)&pw;                                                   \
        _Pragma("unroll")                                                          \
        for (int cf = 0; cf < 4; cf++) {                                           \
            half8 vf = *(const half8*)(Vc + voff[cf]);                             \
            o[cf] = __builtin_amdgcn_mfma_f32_16x16x32_f16(vf, pf, o[cf], 0, 0, 0); \
        }                                                                          \
        __syncthreads();                                                           \
    }

    for (int t = 0; t < 32; t += 2) {
        ATTN_TILE(0, t);
        ATTN_TILE(1, t + 1);
    }
    // final barrier of the loop guarantees all K/V reads done -> smem reusable

    // g-group lsum reduction (lanes r, r+16, r+32, r+48 hold disjoint kv-slots)
    lsum += __shfl_xor(lsum, 16, 64);
    lsum += __shfl_xor(lsum, 32, 64);

    // merge the two kv-halves via LDS (f32, exact split-softmax algebra)
    float* mo = (float*)smem;             // [64 q][68] padded f32
    float* mml = (float*)(smem + 17408);  // [64 q][2] (m, ls)
    int q2 = qs * 16 + r;
    if (hf) {
#pragma unroll
        for (int cf = 0; cf < 4; cf++)
            *(f32x4*)(mo + q2 * 68 + cf * 16 + g * 4) = o[cf];
        if (l < 16) {
            mml[q2 * 2] = m;
            mml[q2 * 2 + 1] = lsum;
        }
    }
    __syncthreads();
    if (!hf) {
        float m1 = mml[q2 * 2], ls1 = mml[q2 * 2 + 1];
        float M = fmaxf(m, m1);
        float w0 = exp2_fast(m - M), w1 = exp2_fast(m1 - M);
        float inv = 1.0f / (w0 * lsum + w1 * ls1);
        w0 *= inv; w1 *= inv;
        int n = q0 + q2;
        int b = bh >> 4, h = bh & 15;
#pragma unroll
        for (int cf = 0; cf < 4; cf++) {
            f32x4 o1 = *(const f32x4*)(mo + q2 * 68 + cf * 16 + g * 4);
            half4v ov;
#pragma unroll
            for (int e = 0; e < 4; e++) ov[e] = (half_t)(o[cf][e] * w0 + o1[e] * w1);
            *(half4v*)(aoh + ((size_t)b * 2048 + n) * 1024 + h * 64 + cf * 16 + g * 4) = ov;
        }
    }
}

// ---------------- proj GEMM: fp16, BK=64, + bias, f32 out ----------------
__global__ __launch_bounds__(256) void gemm_proj(
    const half_t* __restrict__ A, const half_t* __restrict__ Bt,
    const float* __restrict__ bias, float* __restrict__ out) {
    const int K = 1024;
    __shared__ __align__(16) half_t Al[128 * 64];
    __shared__ __align__(16) half_t Bl[128 * 64];
    int tid = threadIdx.x, w = tid >> 6, l = tid & 63;
    int wr = w >> 1, wc = w & 1, g = l >> 4, r = l & 15;
    int m0 = blockIdx.x * 128, n0 = blockIdx.y * 128;
    f32x4 acc[4][4] = {};

    for (int k0 = 0; k0 < K; k0 += 64) {
#pragma unroll
        for (int p = 0; p < 4; p++) {
            int ci = (p * 4 + w) * 64 + l;
            int row = ci >> 3, c = ci & 7;
            int lc = c ^ (row & 7);
            gl_lds16(A + (size_t)(m0 + row) * K + k0 + lc * 8, Al + (p * 4 + w) * 512);
            gl_lds16(Bt + (size_t)(n0 + row) * K + k0 + lc * 8, Bl + (p * 4 + w) * 512);
        }
        __syncthreads();
#pragma unroll
        for (int ks = 0; ks < 2; ks++) {
            half8 af[4], bf[4];
#pragma unroll
            for (int i = 0; i < 4; i++) {
                int row = wr * 64 + i * 16 + r;
                af[i] = *(const half8*)(Al + row * 64 + (((4 * ks + g) ^ (row & 7)) << 3));
                int rowb = wc * 64 + i * 16 + r;
                bf[i] = *(const half8*)(Bl + rowb * 64 + (((4 * ks + g) ^ (rowb & 7)) << 3));
            }
#pragma unroll
            for (int i = 0; i < 4; i++)
#pragma unroll
                for (int j = 0; j < 4; j++)
                    acc[i][j] = __builtin_amdgcn_mfma_f32_16x16x32_f16(af[i], bf[j], acc[i][j], 0, 0, 0);
        }
        __syncthreads();
    }

#pragma unroll
    for (int i = 0; i < 4; i++)
#pragma unroll
        for (int j = 0; j < 4; j++) {
            int gcol = n0 + wc * 64 + j * 16 + r;
            float bv = bias[gcol];
#pragma unroll
            for (int rr = 0; rr < 4; rr++) {
                int grow = m0 + wr * 64 + i * 16 + g * 4 + rr;
                out[(size_t)grow * 1024 + gcol] = acc[i][j][rr] + bv;
            }
        }
}

// ---------------- launch ----------------
extern "C" void kernel_launch(void* const* d_in, const int* in_sizes, int n_in,
                              void* d_out, int out_size, void* d_ws, size_t ws_size,
                              hipStream_t stream) {
    const float* x = (const float*)d_in[0];
    const float* Wqkv = (const float*)d_in[1];
    const float* Wproj = (const float*)d_in[2];
    const float* bproj = (const float*)d_in[3];
    const float* qscale = (const float*)d_in[4];
    const float* kscale = (const float*)d_in[5];
    float* out = (float*)d_out;

    char* ws = (char*)d_ws;
    half_t* xh  = (half_t*)(ws + 0);         //  8.0 MB (4096 x 1024 fp16)
    half_t* wqt = (half_t*)(ws + 8388608);   //  6.0 MB (3072 x 1024 fp16, transposed)
    half_t* wpt = (half_t*)(ws + 14680064);  //  2.0 MB (1024 x 1024 fp16, transposed)
    half_t* qh  = (half_t*)(ws + 16777216);  //  8.0 MB (b,h,n,f)
    half_t* kh  = (half_t*)(ws + 25165824);  //  8.0 MB (b,h,n,f)
    half_t* vth = (half_t*)(ws + 33554432);  //  8.0 MB (b,h,f,n)
    half_t* aoh = (half_t*)(ws + 41943040);  //  8.0 MB (b,n,c)

    prep_all<<<8192, 256, 0, stream>>>(x, Wqkv, Wproj, xh, wqt, wpt);
    gemm_qkv<<<dim3(32, 24), 256, 0, stream>>>(xh, wqt, qscale, kscale, qh, kh, vth);
    attn<<<dim3(32, 32), 512, 0, stream>>>(qh, kh, vth, aoh);
    gemm_proj<<<dim3(32, 8), 256, 0, stream>>>(aoh, wpt, bproj, out);
}

// Round 16
// 123.394 us; speedup vs baseline: 1.4937x; 1.0123x over previous
//
#include <hip/hip_runtime.h>

// Problem constants: B=2, N=2048, C=1024, H=16, hd=64
// x:(2,2048,1024) f32; Wqkv:(1024,3072); Wproj:(1024,1024); bproj:(1024); q_scale,k_scale:(64)
// out:(2,2048,1024) f32

typedef _Float16 half_t;
typedef __attribute__((ext_vector_type(2))) __fp16 fp16x2;
typedef __attribute__((ext_vector_type(4))) _Float16 half4v;
typedef __attribute__((ext_vector_type(8))) _Float16 half8;
typedef __attribute__((ext_vector_type(4))) float f32x4;
typedef __attribute__((ext_vector_type(4))) unsigned uint4v;

#define DI __device__ __forceinline__

DI void gl_lds16(const void* g, void* l) {
    __builtin_amdgcn_global_load_lds((const __attribute__((address_space(1))) void*)g,
                                     (__attribute__((address_space(3))) void*)l, 16, 0, 0);
}

DI float exp2_fast(float x) {
    float r;
    asm("v_exp_f32 %0, %1" : "=v"(r) : "v"(x));
    return r;
}

// v_permlane32_swap_b32: a.rows[2,3] <-> b.rows[0,1] (rows = 16-lane groups)
DI void pl32_swap(unsigned& a, unsigned& b) {
    asm("v_permlane32_swap_b32 %0, %1" : "+v"(a), "+v"(b));
}
// v_permlane16_swap_b32: a.rows[1,3] <-> b.rows[0,2]
DI void pl16_swap(unsigned& a, unsigned& b) {
    asm("v_permlane16_swap_b32 %0, %1" : "+v"(a), "+v"(b));
}

DI unsigned pk_u32(float lo, float hi) {
    fp16x2 t = __builtin_amdgcn_cvt_pkrtz(lo, hi);
    return *(unsigned*)&t;
}

// ---------------- merged prep kernel ----------------
// blocks [0,4096): x f32->fp16 ; [4096,7168): Wqkv transpose->fp16 ; [7168,8192): Wproj
__global__ void prep_all(const float* __restrict__ x, const float* __restrict__ Wqkv,
                         const float* __restrict__ Wproj, half_t* __restrict__ xh,
                         half_t* __restrict__ wqt, half_t* __restrict__ wpt) {
    __shared__ float t[32][33];
    int bid = blockIdx.x;
    if (bid < 4096) {
        int i = (bid * 256 + threadIdx.x) * 4;
        float4 v = *(const float4*)(x + i);
        half4v o;
        o[0] = (half_t)v.x; o[1] = (half_t)v.y; o[2] = (half_t)v.z; o[3] = (half_t)v.w;
        *(half4v*)(xh + i) = o;
    } else if (bid < 4096 + 3072) {
        int i = bid - 4096;
        int c0 = (i % 96) * 32, r0 = (i / 96) * 32;
        int tx = threadIdx.x & 31, ty = threadIdx.x >> 5;
#pragma unroll
        for (int k = 0; k < 4; k++)
            t[ty + 8 * k][tx] = Wqkv[(size_t)(r0 + ty + 8 * k) * 3072 + c0 + tx];
        __syncthreads();
#pragma unroll
        for (int k = 0; k < 4; k++)
            wqt[(size_t)(c0 + ty + 8 * k) * 1024 + r0 + tx] = (half_t)t[tx][ty + 8 * k];
    } else {
        int i = bid - 4096 - 3072;
        int c0 = (i % 32) * 32, r0 = (i / 32) * 32;
        int tx = threadIdx.x & 31, ty = threadIdx.x >> 5;
#pragma unroll
        for (int k = 0; k < 4; k++)
            t[ty + 8 * k][tx] = Wproj[(size_t)(r0 + ty + 8 * k) * 1024 + c0 + tx];
        __syncthreads();
#pragma unroll
        for (int k = 0; k < 4; k++)
            wpt[(size_t)(c0 + ty + 8 * k) * 1024 + r0 + tx] = (half_t)t[tx][ty + 8 * k];
    }
}

// ---------------- QKV GEMM: fp16, BK=32, dbuf LDS (32KB -> ~5 blocks/CU) ------------
// PROVEN R15 (124.9us total). Rows are 4 chunks of 16B; stage/read swizzle
// c ^ ((row>>1)&3) (XOR involution both sides); read = 2-way bank alias (free).
// Fused RMSNorm epilogue (q/k from f32 acc; v stored transposed).
__global__ __launch_bounds__(256, 4) void gemm_qkv(
    const half_t* __restrict__ A, const half_t* __restrict__ Bt,
    const float* __restrict__ qs, const float* __restrict__ ks,
    half_t* __restrict__ qh, half_t* __restrict__ kh, half_t* __restrict__ vth) {
    const int K = 1024;
    __shared__ __align__(16) half_t Al[2][128 * 32];
    __shared__ __align__(16) half_t Bl[2][128 * 32];
    int tid = threadIdx.x;
    int w = tid >> 6, l = tid & 63;
    int wr = w >> 1, wc = w & 1;
    int g = l >> 4, r = l & 15;
    int m0 = blockIdx.x * 128, n0 = blockIdx.y * 128;
    f32x4 acc[4][4] = {};

#define STAGE_QKV(kt, buf)                                                        \
    {                                                                             \
        _Pragma("unroll")                                                         \
        for (int p = 0; p < 2; p++) {                                             \
            int ci = p * 256 + tid;                                               \
            int row = ci >> 2, c = ci & 3, lc = c ^ ((row >> 1) & 3);             \
            gl_lds16(A + (size_t)(m0 + row) * K + (kt) * 32 + lc * 8,             \
                     &Al[buf][0] + ci * 8);                                       \
            gl_lds16(Bt + (size_t)(n0 + row) * K + (kt) * 32 + lc * 8,            \
                     &Bl[buf][0] + ci * 8);                                       \
        }                                                                         \
    }

    STAGE_QKV(0, 0);
    __syncthreads();
    int cur = 0;
    for (int kt = 0; kt < 32; kt++) {
        if (kt < 31) STAGE_QKV(kt + 1, cur ^ 1);
        half8 af[4], bf[4];
#pragma unroll
        for (int i = 0; i < 4; i++) {
            int row = wr * 64 + i * 16 + r;
            af[i] = *(const half8*)(&Al[cur][0] + row * 32 + ((g ^ ((row >> 1) & 3)) << 3));
            int rowb = wc * 64 + i * 16 + r;
            bf[i] = *(const half8*)(&Bl[cur][0] + rowb * 32 + ((g ^ ((rowb >> 1) & 3)) << 3));
        }
#pragma unroll
        for (int i = 0; i < 4; i++)
#pragma unroll
            for (int j = 0; j < 4; j++)
                acc[i][j] = __builtin_amdgcn_mfma_f32_16x16x32_f16(af[i], bf[j], acc[i][j], 0, 0, 0);
        __syncthreads();
        cur ^= 1;
    }

    int tsec = n0 >> 10;  // 0=q, 1=k, 2=v (uniform per block)
    if (tsec == 2) {
#pragma unroll
        for (int i = 0; i < 4; i++)
#pragma unroll
            for (int j = 0; j < 4; j++) {
                int gcol = n0 + wc * 64 + j * 16 + r;
                int h = (gcol >> 6) & 15;
                int f = gcol & 63;
                int growb = m0 + wr * 64 + i * 16 + g * 4;
                int b = growb >> 11;
                int n = growb & 2047;
                half4v pv;
#pragma unroll
                for (int rr = 0; rr < 4; rr++) pv[rr] = (half_t)acc[i][j][rr];
                *(half4v*)(vth + ((size_t)(b * 16 + h) * 64 + f) * 2048 + n) = pv;
            }
    } else {
        const float* sc = (tsec == 0) ? qs : ks;
        half_t* dst = (tsec == 0) ? qh : kh;
        float extra = (tsec == 0) ? (0.125f * 1.44269504f) : 1.0f;  // fold hd^-0.5*log2e into q
        float scv[4];
#pragma unroll
        for (int j = 0; j < 4; j++) scv[j] = sc[j * 16 + r];
#pragma unroll
        for (int i = 0; i < 4; i++)
#pragma unroll
            for (int rr = 0; rr < 4; rr++) {
                float ss = 0.f;
#pragma unroll
                for (int j = 0; j < 4; j++) ss += acc[i][j][rr] * acc[i][j][rr];
#pragma unroll
                for (int d = 1; d < 16; d <<= 1) ss += __shfl_xor(ss, d, 64);
                float inv = extra / (sqrtf(ss) * 0.125f + 1e-8f);  // rms = ||row||/8
                int grow = m0 + wr * 64 + i * 16 + g * 4 + rr;
                int b = grow >> 11;
                int n = grow & 2047;
#pragma unroll
                for (int j = 0; j < 4; j++) {
                    int gcol = n0 + wc * 64 + j * 16 + r;
                    int h = (gcol >> 6) & 15;
                    int f = gcol & 63;
                    dst[((size_t)(b * 16 + h) * 2048 + n) * 64 + f] =
                        (half_t)(acc[i][j][rr] * inv * scv[j]);
                }
            }
    }
}

// ---------------- flash attention: IN-BLOCK kv-split-2, 32 waves/CU ----------------
// EXACT R13/R15 kernel (proven pass, 56.5us). Do NOT change lsum mechanics
// (R6 no-max and R14 ones-MFMA both failed ~5e-2).
__global__ __launch_bounds__(512, 8) void attn(
    const half_t* __restrict__ qh, const half_t* __restrict__ kh,
    const half_t* __restrict__ vth, half_t* __restrict__ aoh) {
    int bh = blockIdx.y;
    int q0 = blockIdx.x * 64;
    int tid = threadIdx.x, w = tid >> 6, l = tid & 63, g = l >> 4, r = l & 15;
    int hf = w >> 2, qs = w & 3, lt = tid & 255;

    const half_t* Qp = qh + (size_t)bh * 2048 * 64;
    const half_t* Kp = kh + (size_t)bh * 2048 * 64 + (size_t)hf * 1024 * 64;
    const half_t* Vp = vth + (size_t)bh * 64 * 2048 + hf * 1024;  // (feat, n)

    __shared__ __align__(16) char smem[32768];
    half_t* Kb[2] = {(half_t*)(smem + hf * 8192), (half_t*)(smem + hf * 8192 + 4096)};
    half_t* Vb[2] = {(half_t*)(smem + 16384 + hf * 8192), (half_t*)(smem + 16384 + hf * 8192 + 4096)};

    int krow = lt >> 3, kc = lt & 7, klc = kc ^ (krow & 7);
    const half_t* kst = Kp + (size_t)krow * 64 + klc * 8;
    int vrow = lt >> 2, vc = lt & 3, vlc = vc ^ ((vrow >> 1) & 3);
    const half_t* vst = Vp + (size_t)vrow * 2048 + vlc * 8;

    int koff[4], voff[4];
#pragma unroll
    for (int ks = 0; ks < 2; ks++)
#pragma unroll
        for (int tt = 0; tt < 2; tt++) {
            int row = tt * 16 + r;
            koff[ks * 2 + tt] = row * 64 + (((ks * 4 + g) ^ (row & 7)) << 3);
        }
#pragma unroll
    for (int cf = 0; cf < 4; cf++) {
        int row = cf * 16 + r;
        voff[cf] = row * 32 + ((g ^ ((row >> 1) & 3)) << 3);
    }

    half8 qf[2];
#pragma unroll
    for (int ks = 0; ks < 2; ks++)
        qf[ks] = *(const half8*)(Qp + (size_t)(q0 + qs * 16 + r) * 64 + ks * 32 + g * 8);

    f32x4 o[4] = {};
    float m = -1e30f, lsum = 0.f;

    gl_lds16(kst, Kb[0] + lt * 8);
    gl_lds16(vst, Vb[0] + lt * 8);
    __syncthreads();

#define ATTN_TILE(BUF, T)                                                          \
    {                                                                              \
        if ((T) < 31) {                                                            \
            gl_lds16(kst + ((T) + 1) * 2048, Kb[(BUF) ^ 1] + lt * 8);              \
            gl_lds16(vst + ((T) + 1) * 32, Vb[(BUF) ^ 1] + lt * 8);                \
        }                                                                          \
        const half_t* Kc = Kb[BUF];                                                \
        const half_t* Vc = Vb[BUF];                                                \
        f32x4 s[2] = {};                                                           \
        _Pragma("unroll")                                                          \
        for (int ks = 0; ks < 2; ks++)                                             \
            _Pragma("unroll")                                                      \
            for (int tt = 0; tt < 2; tt++) {                                       \
                half8 kf = *(const half8*)(Kc + koff[ks * 2 + tt]);                \
                s[tt] = __builtin_amdgcn_mfma_f32_16x16x32_f16(kf, qf[ks], s[tt], 0, 0, 0); \
            }                                                                      \
        float thr = m + 11.0f;                                                     \
        bool ok = true;                                                            \
        _Pragma("unroll")                                                          \
        for (int tt = 0; tt < 2; tt++)                                             \
            _Pragma("unroll")                                                      \
            for (int e = 0; e < 4; e++) ok = ok && (s[tt][e] <= thr);              \
        if (!__all(ok)) {                                                          \
            float mx = fmaxf(fmaxf(s[0][0], s[0][1]), fmaxf(s[0][2], s[0][3]));    \
            mx = fmaxf(mx, fmaxf(fmaxf(s[1][0], s[1][1]), fmaxf(s[1][2], s[1][3]))); \
            mx = fmaxf(mx, __shfl_xor(mx, 16, 64));                                \
            mx = fmaxf(mx, __shfl_xor(mx, 32, 64));                                \
            float mn = fmaxf(m, mx);                                               \
            float fac = exp2_fast(m - mn);                                         \
            lsum *= fac;                                                           \
            _Pragma("unroll")                                                      \
            for (int cf = 0; cf < 4; cf++) {                                       \
                o[cf][0] *= fac; o[cf][1] *= fac; o[cf][2] *= fac; o[cf][3] *= fac; \
            }                                                                      \
            m = mn;                                                                \
        }                                                                          \
        _Pragma("unroll")                                                          \
        for (int tt = 0; tt < 2; tt++)                                             \
            _Pragma("unroll")                                                      \
            for (int e = 0; e < 4; e++) {                                          \
                float p = exp2_fast(s[tt][e] - m);                                 \
                s[tt][e] = p;                                                      \
                lsum += p;                                                         \
            }                                                                      \
        unsigned b0 = pk_u32(s[0][0], s[0][1]);                                    \
        unsigned b1 = pk_u32(s[0][2], s[0][3]);                                    \
        unsigned b2 = pk_u32(s[1][0], s[1][1]);                                    \
        unsigned b3 = pk_u32(s[1][2], s[1][3]);                                    \
        pl32_swap(b0, b2); pl16_swap(b0, b2);                                      \
        pl32_swap(b1, b3); pl16_swap(b1, b3);                                      \
        uint4v pw; pw[0] = b0; pw[1] = b1; pw[2] = b2; pw[3] = b3;                 \
        half8 pf = *(half8*)&pw;                                                   \
        _Pragma("unroll")                                                          \
        for (int cf = 0; cf < 4; cf++) {                                           \
            half8 vf = *(const half8*)(Vc + voff[cf]);                             \
            o[cf] = __builtin_amdgcn_mfma_f32_16x16x32_f16(vf, pf, o[cf], 0, 0, 0); \
        }                                                                          \
        __syncthreads();                                                           \
    }

    for (int t = 0; t < 32; t += 2) {
        ATTN_TILE(0, t);
        ATTN_TILE(1, t + 1);
    }

    lsum += __shfl_xor(lsum, 16, 64);
    lsum += __shfl_xor(lsum, 32, 64);

    float* mo = (float*)smem;             // [64 q][68] padded f32
    float* mml = (float*)(smem + 17408);  // [64 q][2] (m, ls)
    int q2 = qs * 16 + r;
    if (hf) {
#pragma unroll
        for (int cf = 0; cf < 4; cf++)
            *(f32x4*)(mo + q2 * 68 + cf * 16 + g * 4) = o[cf];
        if (l < 16) {
            mml[q2 * 2] = m;
            mml[q2 * 2 + 1] = lsum;
        }
    }
    __syncthreads();
    if (!hf) {
        float m1 = mml[q2 * 2], ls1 = mml[q2 * 2 + 1];
        float M = fmaxf(m, m1);
        float w0 = exp2_fast(m - M), w1 = exp2_fast(m1 - M);
        float inv = 1.0f / (w0 * lsum + w1 * ls1);
        w0 *= inv; w1 *= inv;
        int n = q0 + q2;
        int b = bh >> 4, h = bh & 15;
#pragma unroll
        for (int cf = 0; cf < 4; cf++) {
            f32x4 o1 = *(const f32x4*)(mo + q2 * 68 + cf * 16 + g * 4);
            half4v ov;
#pragma unroll
            for (int e = 0; e < 4; e++) ov[e] = (half_t)(o[cf][e] * w0 + o1[e] * w1);
            *(half4v*)(aoh + ((size_t)b * 2048 + n) * 1024 + h * 64 + cf * 16 + g * 4) = ov;
        }
    }
}

// ---------------- proj GEMM: 64x128 tile, BK=32, dbuf, + bias, f32 out -------------
// Occupancy fix (3rd application of the thesis): old grid (32,8)=256 blocks was
// exactly 1 block/CU (4 waves/CU, the worst in the pipeline). Now tile 64x128,
// grid (64,8)=512 blocks, BK=32 dbuf single-barrier, 24KB LDS -> 2 blocks/CU
// (8 waves/CU). Wave grid 2x2: wave(wr,wc) owns rows wr*32+[0,32), cols
// wc*64+[0,64) -> acc[2][4]. Same swizzle family c^((row>>1)&3) both sides.
__global__ __launch_bounds__(256, 4) void gemm_proj(
    const half_t* __restrict__ A, const half_t* __restrict__ Bt,
    const float* __restrict__ bias, float* __restrict__ out) {
    const int K = 1024;
    __shared__ __align__(16) half_t Al[2][64 * 32];
    __shared__ __align__(16) half_t Bl[2][128 * 32];
    int tid = threadIdx.x, w = tid >> 6, l = tid & 63;
    int wr = w >> 1, wc = w & 1, g = l >> 4, r = l & 15;
    int m0 = blockIdx.x * 64, n0 = blockIdx.y * 128;
    f32x4 acc[2][4] = {};

#define STAGE_PROJ(kt, buf)                                                       \
    {                                                                             \
        {                                                                         \
            int ci = tid;                                                         \
            int row = ci >> 2, c = ci & 3, lc = c ^ ((row >> 1) & 3);             \
            gl_lds16(A + (size_t)(m0 + row) * K + (kt) * 32 + lc * 8,             \
                     &Al[buf][0] + ci * 8);                                       \
        }                                                                         \
        _Pragma("unroll")                                                         \
        for (int p = 0; p < 2; p++) {                                             \
            int ci = p * 256 + tid;                                               \
            int row = ci >> 2, c = ci & 3, lc = c ^ ((row >> 1) & 3);             \
            gl_lds16(Bt + (size_t)(n0 + row) * K + (kt) * 32 + lc * 8,            \
                     &Bl[buf][0] + ci * 8);                                       \
        }                                                                         \
    }

    STAGE_PROJ(0, 0);
    __syncthreads();
    int cur = 0;
    for (int kt = 0; kt < 32; kt++) {
        if (kt < 31) STAGE_PROJ(kt + 1, cur ^ 1);
        half8 af[2], bf[4];
#pragma unroll
        for (int i = 0; i < 2; i++) {
            int row = wr * 32 + i * 16 + r;
            af[i] = *(const half8*)(&Al[cur][0] + row * 32 + ((g ^ ((row >> 1) & 3)) << 3));
        }
#pragma unroll
        for (int j = 0; j < 4; j++) {
            int rowb = wc * 64 + j * 16 + r;
            bf[j] = *(const half8*)(&Bl[cur][0] + rowb * 32 + ((g ^ ((rowb >> 1) & 3)) << 3));
        }
#pragma unroll
        for (int i = 0; i < 2; i++)
#pragma unroll
            for (int j = 0; j < 4; j++)
                acc[i][j] = __builtin_amdgcn_mfma_f32_16x16x32_f16(af[i], bf[j], acc[i][j], 0, 0, 0);
        __syncthreads();
        cur ^= 1;
    }

#pragma unroll
    for (int i = 0; i < 2; i++)
#pragma unroll
        for (int j = 0; j < 4; j++) {
            int gcol = n0 + wc * 64 + j * 16 + r;
            float bv = bias[gcol];
#pragma unroll
            for (int rr = 0; rr < 4; rr++) {
                int grow = m0 + wr * 32 + i * 16 + g * 4 + rr;
                out[(size_t)grow * 1024 + gcol] = acc[i][j][rr] + bv;
            }
        }
}

// ---------------- launch ----------------
extern "C" void kernel_launch(void* const* d_in, const int* in_sizes, int n_in,
                              void* d_out, int out_size, void* d_ws, size_t ws_size,
                              hipStream_t stream) {
    const float* x = (const float*)d_in[0];
    const float* Wqkv = (const float*)d_in[1];
    const float* Wproj = (const float*)d_in[2];
    const float* bproj = (const float*)d_in[3];
    const float* qscale = (const float*)d_in[4];
    const float* kscale = (const float*)d_in[5];
    float* out = (float*)d_out;

    char* ws = (char*)d_ws;
    half_t* xh  = (half_t*)(ws + 0);         //  8.0 MB (4096 x 1024 fp16)
    half_t* wqt = (half_t*)(ws + 8388608);   //  6.0 MB (3072 x 1024 fp16, transposed)
    half_t* wpt = (half_t*)(ws + 14680064);  //  2.0 MB (1024 x 1024 fp16, transposed)
    half_t* qh  = (half_t*)(ws + 16777216);  //  8.0 MB (b,h,n,f)
    half_t* kh  = (half_t*)(ws + 25165824);  //  8.0 MB (b,h,n,f)
    half_t* vth = (half_t*)(ws + 33554432);  //  8.0 MB (b,h,f,n)
    half_t* aoh = (half_t*)(ws + 41943040);  //  8.0 MB (b,n,c)

    prep_all<<<8192, 256, 0, stream>>>(x, Wqkv, Wproj, xh, wqt, wpt);
    gemm_qkv<<<dim3(32, 24), 256, 0, stream>>>(xh, wqt, qscale, kscale, qh, kh, vth);
    attn<<<dim3(32, 32), 512, 0, stream>>>(qh, kh, vth, aoh);
    gemm_proj<<<dim3(64, 8), 256, 0, stream>>>(aoh, wpt, bproj, out);
}